// Round 8
// baseline (224.395 us; speedup 1.0000x reference)
//
#include <hip/hip_runtime.h>
#include <math.h>

// GatedGCN forward, fp32 in/out. D = U = 96. 4 dispatches:
//   memset(cnt8) | k_fuse1: W-convert + Xb + newX MFMA + single-pass per-XCD
//   padded-CSR fill | k_agg: 8-list gather-aggregate | k_gateM: gate + combine.
// R7 lesson: XCD-partitioned fill with 8x edge re-scan cost ~55us; per-XCD
// private lists give single-pass fill with XCD-local writes (no re-scan, no
// line sharing). R6 lesson: no cooperative grid.sync on this chip.

#define DU 96
#define DU4 24
#define NCH 12   // 8-dim (16 B) chunks per row for the gather
#define CAP 32   // slots per (XCD, dest) list; per-list degree ~Poisson(2)

typedef unsigned int uint;
typedef unsigned short ushort;
typedef __attribute__((ext_vector_type(8))) short short8;
typedef __attribute__((ext_vector_type(4))) float f32x4;

__device__ inline uint bf16r(float x) {  // fp32 -> bf16 bits, round-nearest-even
  uint u = __float_as_uint(x);
  return (u + 0x7FFFu + ((u >> 16) & 1u)) >> 16;
}

// ---------- k_fuse1: per-block W->LDS, X->Xs/Xb, newX MFMA, then CSR fill ----
__global__ __launch_bounds__(256) void k_fuse1(
    const float* __restrict__ X, const float* __restrict__ Wn,
    const float* __restrict__ bn, const float* __restrict__ Wgi,
    const float* __restrict__ Wgn, const int* __restrict__ row,
    const int* __restrict__ col, const float* __restrict__ a_vals,
    ushort* __restrict__ Xb, ushort* __restrict__ newXb,
    ushort* __restrict__ WTgi, ushort* __restrict__ WTgn,
    int* __restrict__ cnt8, int2* __restrict__ epad8, int N, int E, int ntile) {
  __shared__ ushort WL[9216];     // Wn bf16, MFMA-fragment-ordered (18 KB)
  __shared__ ushort Xs[64][104];  // X tile bf16 (13 KB); reused as Y staging
  const int tid = threadIdx.x;
  const int lane = tid & 63, w = tid >> 6;
  const int m = lane & 15, q = lane >> 4;

  if ((int)blockIdx.x < ntile) {
    // blocks 0/1: also emit gate weights bf16 (row-major WT[n*96+k]) for k_gateM
    if (blockIdx.x == 0) {
      for (int i = tid; i < DU * DU; i += 256) {
        int n = i / DU, k = i % DU;
        WTgi[i] = (ushort)bf16r(Wgi[k * DU + n]);
      }
    } else if (blockIdx.x == 1) {
      for (int i = tid; i < DU * DU; i += 256) {
        int n = i / DU, k = i % DU;
        WTgn[i] = (ushort)bf16r(Wgn[k * DU + n]);
      }
    }
    // Wn -> WL in exact B-fragment order: frag (ks,t), lane, j  ->
    // element k = ks*32+(lane>>4)*8+j, n = t*16+(lane&15)
    for (int idx = tid; idx < 9216; idx += 256) {
      int j = idx & 7, ln = (idx >> 3) & 63, tk = idx >> 9;  // tk = ks*6+t
      int ks = tk / 6, t = tk % 6;
      int k = ks * 32 + (ln >> 4) * 8 + j;
      int n = t * 16 + (ln & 15);
      WL[idx] = (ushort)bf16r(Wn[k * DU + n]);
    }
    // own 64 X rows -> Xs (LDS) + Xb (global)
    const int row0 = blockIdx.x * 64;
    for (int i = tid; i < 64 * 48; i += 256) {
      int r = i / 48, cu = i % 48;
      int gr = row0 + r;
      uint packed = 0;
      if (gr < N) {
        float2 v = ((const float2*)X)[(size_t)gr * 48 + cu];
        packed = bf16r(v.x) | (bf16r(v.y) << 16);
        ((uint*)Xb)[(size_t)gr * 48 + cu] = packed;
      }
      *(uint*)&Xs[r][cu * 2] = packed;
    }
    __syncthreads();

    f32x4 acc[6];
#pragma unroll
    for (int t = 0; t < 6; ++t) acc[t] = (f32x4){0.f, 0.f, 0.f, 0.f};
#pragma unroll
    for (int ks = 0; ks < 3; ++ks) {
      short8 af = *(const short8*)&Xs[w * 16 + m][ks * 32 + q * 8];
#pragma unroll
      for (int t = 0; t < 6; ++t) {
        short8 bf = *(const short8*)&WL[((ks * 6 + t) * 64 + lane) * 8];
        acc[t] = __builtin_amdgcn_mfma_f32_16x16x32_bf16(af, bf, acc[t], 0, 0, 0);
      }
    }
    __syncthreads();  // all A-frag reads done; reuse Xs as output staging
#pragma unroll
    for (int t = 0; t < 6; ++t) {
      int c = t * 16 + m;
      float bb = bn[c];
#pragma unroll
      for (int i = 0; i < 4; ++i)
        Xs[w * 16 + q * 4 + i][c] = (ushort)bf16r(acc[t][i] + bb);
    }
    __syncthreads();
    for (int i = tid; i < 64 * 48; i += 256) {
      int r = i / 48, cu = i % 48;
      int gr = row0 + r;
      if (gr < N) ((uint*)newXb)[(size_t)gr * 48 + cu] = *(uint*)&Xs[r][cu * 2];
    }
  }

  // Single-pass padded-CSR fill into per-XCD private region g = blockIdx&7
  // (round-robin XCD heuristic). All writes/atomics for region g come only
  // from XCD g's blocks -> no cross-XCD line sharing (R4: 8x writeback
  // otherwise). Each edge visited exactly once (R7 re-scanned 8x).
  // Correctness never depends on the XCD mapping (unique (g,d,slot)).
  {
    const int g = blockIdx.x & 7;
    int* cnt = cnt8 + (size_t)g * N;
    int2* ep = epad8 + (size_t)g * N * CAP;
    for (int i = blockIdx.x * 256 + tid; i < E; i += gridDim.x * 256) {
      int d = row[i];
      int slot = atomicAdd(&cnt[d], 1);
      if (slot < CAP)  // P(overflow) ~ 0 for per-list Poisson(2); guard OOB
        ep[(size_t)d * CAP + slot] = make_int2(col[i], __float_as_int(a_vals[i]));
    }
  }
}

// ---------- k_agg: aggb[r] = bf16(sum over 8 lists of a_e * newXb[col_e]) ----
// One thread per (row, 16 B chunk): 12 chunk-threads/row, uint4 gathers.
__global__ __launch_bounds__(256) void k_agg(const ushort* __restrict__ newXb,
                                             const int* __restrict__ cnt8,
                                             const int2* __restrict__ epad8,
                                             ushort* __restrict__ aggb, int N) {
  int i = blockIdx.x * 256 + threadIdx.x;
  int r = i / NCH;
  int c = i % NCH;  // dims c*8 .. c*8+7
  if (r >= N) return;
  float acc[8];
#pragma unroll
  for (int j = 0; j < 8; ++j) acc[j] = 0.f;

#pragma unroll
  for (int g = 0; g < 8; ++g) {
    int e1 = cnt8[(size_t)g * N + r];
    if (e1 > CAP) e1 = CAP;
    const int2* ep = epad8 + ((size_t)g * N + r) * CAP;
    int e = 0;
    for (; e + 2 <= e1; e += 2) {
      int2 p0 = ep[e + 0];
      int2 p1 = ep[e + 1];
      uint4 v0 = *(const uint4*)(newXb + (size_t)p0.x * DU + c * 8);
      uint4 v1 = *(const uint4*)(newXb + (size_t)p1.x * DU + c * 8);
      float a0 = __int_as_float(p0.y), a1 = __int_as_float(p1.y);
      acc[0] = fmaf(a0, __uint_as_float(v0.x << 16), acc[0]);
      acc[1] = fmaf(a0, __uint_as_float(v0.x & 0xFFFF0000u), acc[1]);
      acc[2] = fmaf(a0, __uint_as_float(v0.y << 16), acc[2]);
      acc[3] = fmaf(a0, __uint_as_float(v0.y & 0xFFFF0000u), acc[3]);
      acc[4] = fmaf(a0, __uint_as_float(v0.z << 16), acc[4]);
      acc[5] = fmaf(a0, __uint_as_float(v0.z & 0xFFFF0000u), acc[5]);
      acc[6] = fmaf(a0, __uint_as_float(v0.w << 16), acc[6]);
      acc[7] = fmaf(a0, __uint_as_float(v0.w & 0xFFFF0000u), acc[7]);
      acc[0] = fmaf(a1, __uint_as_float(v1.x << 16), acc[0]);
      acc[1] = fmaf(a1, __uint_as_float(v1.x & 0xFFFF0000u), acc[1]);
      acc[2] = fmaf(a1, __uint_as_float(v1.y << 16), acc[2]);
      acc[3] = fmaf(a1, __uint_as_float(v1.y & 0xFFFF0000u), acc[3]);
      acc[4] = fmaf(a1, __uint_as_float(v1.z << 16), acc[4]);
      acc[5] = fmaf(a1, __uint_as_float(v1.z & 0xFFFF0000u), acc[5]);
      acc[6] = fmaf(a1, __uint_as_float(v1.w << 16), acc[6]);
      acc[7] = fmaf(a1, __uint_as_float(v1.w & 0xFFFF0000u), acc[7]);
    }
    if (e < e1) {
      int2 p = ep[e];
      uint4 v = *(const uint4*)(newXb + (size_t)p.x * DU + c * 8);
      float a = __int_as_float(p.y);
      acc[0] = fmaf(a, __uint_as_float(v.x << 16), acc[0]);
      acc[1] = fmaf(a, __uint_as_float(v.x & 0xFFFF0000u), acc[1]);
      acc[2] = fmaf(a, __uint_as_float(v.y << 16), acc[2]);
      acc[3] = fmaf(a, __uint_as_float(v.y & 0xFFFF0000u), acc[3]);
      acc[4] = fmaf(a, __uint_as_float(v.z << 16), acc[4]);
      acc[5] = fmaf(a, __uint_as_float(v.z & 0xFFFF0000u), acc[5]);
      acc[6] = fmaf(a, __uint_as_float(v.w << 16), acc[6]);
      acc[7] = fmaf(a, __uint_as_float(v.w & 0xFFFF0000u), acc[7]);
    }
  }
  uint4 o;
  o.x = bf16r(acc[0]) | (bf16r(acc[1]) << 16);
  o.y = bf16r(acc[2]) | (bf16r(acc[3]) << 16);
  o.z = bf16r(acc[4]) | (bf16r(acc[5]) << 16);
  o.w = bf16r(acc[6]) | (bf16r(acc[7]) << 16);
  *(uint4*)(aggb + (size_t)r * DU + c * 8) = o;
}

// ---------- k_gateM: z = Xb@Wgi + aggb@Wgn + b; out = X + g*(agg-X) ----------
__global__ __launch_bounds__(256) void k_gateM(const ushort* __restrict__ Xb,
                                               const ushort* __restrict__ aggb,
                                               const ushort* __restrict__ WTgi,
                                               const ushort* __restrict__ WTgn,
                                               const float* __restrict__ bgi,
                                               const float* __restrict__ bgn,
                                               const float* __restrict__ X,
                                               float* __restrict__ Out, int N) {
  __shared__ float Gs[64][100];
  const int tid = threadIdx.x;
  const int lane = tid & 63, w = tid >> 6;
  const int m = lane & 15, q = lane >> 4;
  const int row0 = blockIdx.x * 64;
  int ar = row0 + w * 16 + m;
  if (ar > N - 1) ar = N - 1;

  f32x4 acc[6];
#pragma unroll
  for (int t = 0; t < 6; ++t) acc[t] = (f32x4){0.f, 0.f, 0.f, 0.f};

#pragma unroll
  for (int ks = 0; ks < 3; ++ks) {
    short8 af = *(const short8*)(Xb + (size_t)ar * DU + ks * 32 + q * 8);
#pragma unroll
    for (int t = 0; t < 6; ++t) {
      short8 bf = *(const short8*)(WTgi + (size_t)(t * 16 + m) * DU + ks * 32 + q * 8);
      acc[t] = __builtin_amdgcn_mfma_f32_16x16x32_bf16(af, bf, acc[t], 0, 0, 0);
    }
  }
#pragma unroll
  for (int ks = 0; ks < 3; ++ks) {
    short8 af = *(const short8*)(aggb + (size_t)ar * DU + ks * 32 + q * 8);
#pragma unroll
    for (int t = 0; t < 6; ++t) {
      short8 bf = *(const short8*)(WTgn + (size_t)(t * 16 + m) * DU + ks * 32 + q * 8);
      acc[t] = __builtin_amdgcn_mfma_f32_16x16x32_bf16(af, bf, acc[t], 0, 0, 0);
    }
  }

#pragma unroll
  for (int t = 0; t < 6; ++t) {
    int c = t * 16 + m;
    float bb = bgi[c] + bgn[c];
#pragma unroll
    for (int i = 0; i < 4; ++i) {
      float z = acc[t][i] + bb;
      Gs[w * 16 + q * 4 + i][c] = 1.f / (1.f + __expf(-z));
    }
  }
  __syncthreads();

  for (int j = tid; j < 64 * DU4; j += 256) {
    int r = j / DU4, c = j % DU4;
    int gr = row0 + r;
    if (gr < N) {
      float4 xv = ((const float4*)X)[(size_t)gr * DU4 + c];
      uint2 av = ((const uint2*)aggb)[(size_t)gr * DU4 + c];
      float a0 = __uint_as_float(av.x << 16);
      float a1 = __uint_as_float(av.x & 0xFFFF0000u);
      float a2 = __uint_as_float(av.y << 16);
      float a3 = __uint_as_float(av.y & 0xFFFF0000u);
      const float* gp = &Gs[r][c * 4];
      float4 o;
      o.x = xv.x + gp[0] * (a0 - xv.x);
      o.y = xv.y + gp[1] * (a1 - xv.y);
      o.z = xv.z + gp[2] * (a2 - xv.z);
      o.w = xv.w + gp[3] * (a3 - xv.w);
      ((float4*)Out)[(size_t)gr * DU4 + c] = o;
    }
  }
}

extern "C" void kernel_launch(void* const* d_in, const int* in_sizes, int n_in,
                              void* d_out, int out_size, void* d_ws, size_t ws_size,
                              hipStream_t stream) {
  const float* X      = (const float*)d_in[0];
  const float* a_vals = (const float*)d_in[1];
  const float* Wn     = (const float*)d_in[2];
  const float* bn     = (const float*)d_in[3];
  const float* Wgi    = (const float*)d_in[4];
  const float* bgi    = (const float*)d_in[5];
  const float* Wgn    = (const float*)d_in[6];
  const float* bgn    = (const float*)d_in[7];
  const int*   row    = (const int*)d_in[8];
  const int*   col    = (const int*)d_in[9];
  float* out = (float*)d_out;

  const int N = in_sizes[0] / DU;
  const int E = in_sizes[1];
  const int ntile = (N + 63) / 64;          // 782
  const int G1 = ((ntile + 7) / 8) * 8;     // 784, multiple of 8 for XCD fill

  // Workspace (~133 MB of 256 MiB): epad8 first for 16B alignment
  int2*   epad8 = (int2*)d_ws;                        // 8*N*CAP int2 (102.4 MB)
  ushort* Xb    = (ushort*)(epad8 + (size_t)8 * N * CAP);  // 9.6 MB
  ushort* newXb = Xb + (size_t)N * DU;                // 9.6 MB
  ushort* aggb  = newXb + (size_t)N * DU;             // 9.6 MB
  ushort* WTgi  = aggb + (size_t)N * DU;              // 18 KB
  ushort* WTgn  = WTgi + DU * DU;                     // 18 KB
  int*    cnt8  = (int*)(WTgn + DU * DU);             // 8*N ints (1.6 MB)

  hipMemsetAsync(cnt8, 0, (size_t)8 * N * sizeof(int), stream);

  k_fuse1<<<G1, 256, 0, stream>>>(X, Wn, bn, Wgi, Wgn, row, col, a_vals,
                                  Xb, newXb, WTgi, WTgn, cnt8, epad8, N, E, ntile);
  k_agg  <<<((size_t)N * NCH + 255) / 256, 256, 0, stream>>>(newXb, cnt8, epad8, aggb, N);
  k_gateM<<<ntile, 256, 0, stream>>>(Xb, aggb, WTgi, WTgn, bgi, bgn, X, out, N);
}

// Round 9
// 197.817 us; speedup vs baseline: 1.1344x; 1.1344x over previous
//
#include <hip/hip_runtime.h>
#include <math.h>

// GatedGCN forward, fp32 in/out. D = U = 96. 3 dispatches:
//   memset(cnt) | k_fuse1: W-convert(LDS) + Xb + newX MFMA + padded-CSR fill
//   | k_aggGate: per-64-row-block CSR gather into LDS + gate MFMA + combine.
// R6: no cooperative grid.sync (barrier >> 12us dispatch). R8: keep the CSR
// write region small (25.6 MB) - per-XCD-private 102 MB regions thrash L2.

#define DU 96
#define DU4 24
#define CAP 64  // slots per dest; Poisson(16) tail P(>=64) ~ 1e-22

typedef unsigned int uint;
typedef unsigned short ushort;
typedef __attribute__((ext_vector_type(8))) short short8;
typedef __attribute__((ext_vector_type(4))) float f32x4;

__device__ inline uint bf16r(float x) {  // fp32 -> bf16 bits, round-nearest-even
  uint u = __float_as_uint(x);
  return (u + 0x7FFFu + ((u >> 16) & 1u)) >> 16;
}

// ---------- k_fuse1: per-block W->LDS, X->Xs/Xb, newX MFMA, then CSR fill ----
__global__ __launch_bounds__(256) void k_fuse1(
    const float* __restrict__ X, const float* __restrict__ Wn,
    const float* __restrict__ bn, const float* __restrict__ Wgi,
    const float* __restrict__ Wgn, const int* __restrict__ row,
    const int* __restrict__ col, const float* __restrict__ a_vals,
    ushort* __restrict__ Xb, ushort* __restrict__ newXb,
    ushort* __restrict__ WTgi, ushort* __restrict__ WTgn,
    int* __restrict__ cnt, int2* __restrict__ epad, int N, int E, int ntile) {
  __shared__ ushort WL[9216];     // Wn bf16, MFMA-fragment-ordered (18 KB)
  __shared__ ushort Xs[64][104];  // X tile bf16 (13 KB); reused as Y staging
  const int tid = threadIdx.x;
  const int lane = tid & 63, w = tid >> 6;
  const int m = lane & 15, q = lane >> 4;

  if ((int)blockIdx.x < ntile) {
    // blocks 0/1: emit gate weights bf16 (row-major WT[n*96+k]) for k_aggGate
    if (blockIdx.x == 0) {
      for (int i = tid; i < DU * DU; i += 256) {
        int n = i / DU, k = i % DU;
        WTgi[i] = (ushort)bf16r(Wgi[k * DU + n]);
      }
    } else if (blockIdx.x == 1) {
      for (int i = tid; i < DU * DU; i += 256) {
        int n = i / DU, k = i % DU;
        WTgn[i] = (ushort)bf16r(Wgn[k * DU + n]);
      }
    }
    // Wn -> WL in exact B-fragment order: frag (ks,t), lane, j  ->
    // element k = ks*32+(lane>>4)*8+j, n = t*16+(lane&15)
    for (int idx = tid; idx < 9216; idx += 256) {
      int j = idx & 7, ln = (idx >> 3) & 63, tk = idx >> 9;  // tk = ks*6+t
      int ks = tk / 6, t = tk % 6;
      int k = ks * 32 + (ln >> 4) * 8 + j;
      int n = t * 16 + (ln & 15);
      WL[idx] = (ushort)bf16r(Wn[k * DU + n]);
    }
    // own 64 X rows -> Xs (LDS) + Xb (global)
    const int row0 = blockIdx.x * 64;
    for (int i = tid; i < 64 * 48; i += 256) {
      int r = i / 48, cu = i % 48;
      int gr = row0 + r;
      uint packed = 0;
      if (gr < N) {
        float2 v = ((const float2*)X)[(size_t)gr * 48 + cu];
        packed = bf16r(v.x) | (bf16r(v.y) << 16);
        ((uint*)Xb)[(size_t)gr * 48 + cu] = packed;
      }
      *(uint*)&Xs[r][cu * 2] = packed;
    }
    __syncthreads();

    f32x4 acc[6];
#pragma unroll
    for (int t = 0; t < 6; ++t) acc[t] = (f32x4){0.f, 0.f, 0.f, 0.f};
#pragma unroll
    for (int ks = 0; ks < 3; ++ks) {
      short8 af = *(const short8*)&Xs[w * 16 + m][ks * 32 + q * 8];
#pragma unroll
      for (int t = 0; t < 6; ++t) {
        short8 bf = *(const short8*)&WL[((ks * 6 + t) * 64 + lane) * 8];
        acc[t] = __builtin_amdgcn_mfma_f32_16x16x32_bf16(af, bf, acc[t], 0, 0, 0);
      }
    }
    __syncthreads();  // all A-frag reads done; reuse Xs as output staging
#pragma unroll
    for (int t = 0; t < 6; ++t) {
      int c = t * 16 + m;
      float bb = bn[c];
#pragma unroll
      for (int i = 0; i < 4; ++i)
        Xs[w * 16 + q * 4 + i][c] = (ushort)bf16r(acc[t][i] + bb);
    }
    __syncthreads();
    for (int i = tid; i < 64 * 48; i += 256) {
      int r = i / 48, cu = i % 48;
      int gr = row0 + r;
      if (gr < N) ((uint*)newXb)[(size_t)gr * 48 + cu] = *(uint*)&Xs[r][cu * 2];
    }
  }

  // Padded-CSR fill, XCD-partitioned by dest range (g = blockIdx&7 -> same XCD
  // under round-robin dispatch). Nontemporal 8B store: skip write-allocate of
  // the poisoned line (suspected RFO stall; neutral if theory wrong).
  {
    const int g = blockIdx.x & 7;
    const int sub = blockIdx.x >> 3;
    const int nsub = gridDim.x >> 3;
    const int d0 = (int)((long long)N * g >> 3);
    const int d1 = (int)((long long)N * (g + 1) >> 3);
    for (int i = sub * 256 + tid; i < E; i += nsub * 256) {
      int d = row[i];
      if (d >= d0 && d < d1) {
        int slot = atomicAdd(&cnt[d], 1);
        long long pv = (long long)(uint)col[i] |
                       ((long long)(uint)__float_as_uint(a_vals[i]) << 32);
        __builtin_nontemporal_store(pv, (long long*)&epad[(size_t)d * CAP + slot]);
      }
    }
  }
}

// ---------- k_aggGate: per-block CSR gather -> LDS, gate MFMA, combine ------
// 64 rows/block. Agg: 1536 (row,4-dim) tasks on 256 threads, unroll-4 gathers.
// Then z = Xb@Wgi + As@Wgn + b (MFMA, A-frags for phase 2 from LDS),
// out = X + sigmoid(z)*(agg - X).
__global__ __launch_bounds__(256) void k_aggGate(
    const ushort* __restrict__ Xb, const ushort* __restrict__ newXb,
    const int* __restrict__ cnt, const int2* __restrict__ epad,
    const ushort* __restrict__ WTgi, const ushort* __restrict__ WTgn,
    const float* __restrict__ bgi, const float* __restrict__ bgn,
    const float* __restrict__ X, float* __restrict__ Out, int N) {
  __shared__ ushort As[64][104];  // agg tile bf16 (13.3 KB)
  __shared__ float Gs[64][100];   // gate tile fp32 (25.6 KB)
  const int tid = threadIdx.x;
  const int lane = tid & 63, w = tid >> 6;
  const int m = lane & 15, q = lane >> 4;
  const int row0 = blockIdx.x * 64;

  // ---- Aggregation into As ----
#pragma unroll
  for (int p = 0; p < 6; ++p) {
    int j = p * 256 + tid;       // 1536 tasks
    int lr = j / DU4, c = j % DU4;
    int r = row0 + lr;
    float4 accA = make_float4(0.f, 0.f, 0.f, 0.f);
    float4 accB = make_float4(0.f, 0.f, 0.f, 0.f);
    if (r < N) {
      int e1 = cnt[r];
      if (e1 > CAP) e1 = CAP;
      const int2* ep = epad + (size_t)r * CAP;
      int e = 0;
      for (; e + 4 <= e1; e += 4) {
        int2 p0 = ep[e + 0];
        int2 p1 = ep[e + 1];
        int2 p2 = ep[e + 2];
        int2 p3 = ep[e + 3];
        uint2 v0 = *(const uint2*)(newXb + (size_t)p0.x * DU + c * 4);
        uint2 v1 = *(const uint2*)(newXb + (size_t)p1.x * DU + c * 4);
        uint2 v2 = *(const uint2*)(newXb + (size_t)p2.x * DU + c * 4);
        uint2 v3 = *(const uint2*)(newXb + (size_t)p3.x * DU + c * 4);
        float a0 = __int_as_float(p0.y), a1 = __int_as_float(p1.y);
        float a2 = __int_as_float(p2.y), a3 = __int_as_float(p3.y);
        accA.x = fmaf(a0, __uint_as_float(v0.x << 16), accA.x);
        accA.y = fmaf(a0, __uint_as_float(v0.x & 0xFFFF0000u), accA.y);
        accA.z = fmaf(a0, __uint_as_float(v0.y << 16), accA.z);
        accA.w = fmaf(a0, __uint_as_float(v0.y & 0xFFFF0000u), accA.w);
        accB.x = fmaf(a1, __uint_as_float(v1.x << 16), accB.x);
        accB.y = fmaf(a1, __uint_as_float(v1.x & 0xFFFF0000u), accB.y);
        accB.z = fmaf(a1, __uint_as_float(v1.y << 16), accB.z);
        accB.w = fmaf(a1, __uint_as_float(v1.y & 0xFFFF0000u), accB.w);
        accA.x = fmaf(a2, __uint_as_float(v2.x << 16), accA.x);
        accA.y = fmaf(a2, __uint_as_float(v2.x & 0xFFFF0000u), accA.y);
        accA.z = fmaf(a2, __uint_as_float(v2.y << 16), accA.z);
        accA.w = fmaf(a2, __uint_as_float(v2.y & 0xFFFF0000u), accA.w);
        accB.x = fmaf(a3, __uint_as_float(v3.x << 16), accB.x);
        accB.y = fmaf(a3, __uint_as_float(v3.x & 0xFFFF0000u), accB.y);
        accB.z = fmaf(a3, __uint_as_float(v3.y << 16), accB.z);
        accB.w = fmaf(a3, __uint_as_float(v3.y & 0xFFFF0000u), accB.w);
      }
      for (; e < e1; ++e) {
        int2 pp = ep[e];
        float a = __int_as_float(pp.y);
        uint2 v = *(const uint2*)(newXb + (size_t)pp.x * DU + c * 4);
        accA.x = fmaf(a, __uint_as_float(v.x << 16), accA.x);
        accA.y = fmaf(a, __uint_as_float(v.x & 0xFFFF0000u), accA.y);
        accA.z = fmaf(a, __uint_as_float(v.y << 16), accA.z);
        accA.w = fmaf(a, __uint_as_float(v.y & 0xFFFF0000u), accA.w);
      }
      accA.x += accB.x; accA.y += accB.y; accA.z += accB.z; accA.w += accB.w;
    }
    uint2 o;
    o.x = bf16r(accA.x) | (bf16r(accA.y) << 16);
    o.y = bf16r(accA.z) | (bf16r(accA.w) << 16);
    *(uint2*)&As[lr][c * 4] = o;
  }
  __syncthreads();

  // ---- Gate MFMA ----
  int ar = row0 + w * 16 + m;
  if (ar > N - 1) ar = N - 1;
  const int lr = w * 16 + m;  // local row for LDS A-frags

  f32x4 acc[6];
#pragma unroll
  for (int t = 0; t < 6; ++t) acc[t] = (f32x4){0.f, 0.f, 0.f, 0.f};

#pragma unroll
  for (int ks = 0; ks < 3; ++ks) {
    short8 af = *(const short8*)(Xb + (size_t)ar * DU + ks * 32 + q * 8);
#pragma unroll
    for (int t = 0; t < 6; ++t) {
      short8 bf = *(const short8*)(WTgi + (size_t)(t * 16 + m) * DU + ks * 32 + q * 8);
      acc[t] = __builtin_amdgcn_mfma_f32_16x16x32_bf16(af, bf, acc[t], 0, 0, 0);
    }
  }
#pragma unroll
  for (int ks = 0; ks < 3; ++ks) {
    short8 af = *(const short8*)&As[lr][ks * 32 + q * 8];
#pragma unroll
    for (int t = 0; t < 6; ++t) {
      short8 bf = *(const short8*)(WTgn + (size_t)(t * 16 + m) * DU + ks * 32 + q * 8);
      acc[t] = __builtin_amdgcn_mfma_f32_16x16x32_bf16(af, bf, acc[t], 0, 0, 0);
    }
  }

#pragma unroll
  for (int t = 0; t < 6; ++t) {
    int c = t * 16 + m;
    float bb = bgi[c] + bgn[c];
#pragma unroll
    for (int i = 0; i < 4; ++i) {
      float z = acc[t][i] + bb;
      Gs[w * 16 + q * 4 + i][c] = 1.f / (1.f + __expf(-z));
    }
  }
  __syncthreads();

  // ---- Epilogue: out = x + g*(agg - x); agg from As (LDS) ----
  for (int j = tid; j < 64 * DU4; j += 256) {
    int r = j / DU4, c = j % DU4;
    int gr = row0 + r;
    if (gr < N) {
      float4 xv = ((const float4*)X)[(size_t)gr * DU4 + c];
      uint2 av = *(const uint2*)&As[r][c * 4];
      float a0 = __uint_as_float(av.x << 16);
      float a1 = __uint_as_float(av.x & 0xFFFF0000u);
      float a2 = __uint_as_float(av.y << 16);
      float a3 = __uint_as_float(av.y & 0xFFFF0000u);
      const float* gp = &Gs[r][c * 4];
      float4 o;
      o.x = xv.x + gp[0] * (a0 - xv.x);
      o.y = xv.y + gp[1] * (a1 - xv.y);
      o.z = xv.z + gp[2] * (a2 - xv.z);
      o.w = xv.w + gp[3] * (a3 - xv.w);
      ((float4*)Out)[(size_t)gr * DU4 + c] = o;
    }
  }
}

extern "C" void kernel_launch(void* const* d_in, const int* in_sizes, int n_in,
                              void* d_out, int out_size, void* d_ws, size_t ws_size,
                              hipStream_t stream) {
  const float* X      = (const float*)d_in[0];
  const float* a_vals = (const float*)d_in[1];
  const float* Wn     = (const float*)d_in[2];
  const float* bn     = (const float*)d_in[3];
  const float* Wgi    = (const float*)d_in[4];
  const float* bgi    = (const float*)d_in[5];
  const float* Wgn    = (const float*)d_in[6];
  const float* bgn    = (const float*)d_in[7];
  const int*   row    = (const int*)d_in[8];
  const int*   col    = (const int*)d_in[9];
  float* out = (float*)d_out;

  const int N = in_sizes[0] / DU;
  const int E = in_sizes[1];
  const int ntile = (N + 63) / 64;          // 782
  const int G1 = ((ntile + 7) / 8) * 8;     // 784, multiple of 8 for XCD fill

  // Workspace (~45 MB of 256 MiB): epad first for 16B alignment
  int2*   epad  = (int2*)d_ws;                        // N*CAP + CAP guard (25.6 MB)
  ushort* Xb    = (ushort*)(epad + (size_t)N * CAP + CAP);  // 9.6 MB
  ushort* newXb = Xb + (size_t)N * DU;                // 9.6 MB
  ushort* WTgi  = newXb + (size_t)N * DU;             // 18 KB
  ushort* WTgn  = WTgi + DU * DU;                     // 18 KB
  int*    cnt   = (int*)(WTgn + DU * DU);             // N ints

  hipMemsetAsync(cnt, 0, (size_t)N * sizeof(int), stream);

  k_fuse1<<<G1, 256, 0, stream>>>(X, Wn, bn, Wgi, Wgn, row, col, a_vals,
                                  Xb, newXb, WTgi, WTgn, cnt, epad, N, E, ntile);
  k_aggGate<<<ntile, 256, 0, stream>>>(Xb, newXb, cnt, epad, WTgi, WTgn,
                                       bgi, bgn, X, out, N);
}